// Round 3
// baseline (377.785 us; speedup 1.0000x reference)
//
#include <hip/hip_runtime.h>
#include <cstdint>
#include <cstddef>

#define DI __device__ __forceinline__

using f32x4  = __attribute__((ext_vector_type(4))) float;
using bf16x8 = __attribute__((ext_vector_type(8))) short;
using u32x2  = __attribute__((ext_vector_type(2))) unsigned int;
using u32x4  = __attribute__((ext_vector_type(4))) unsigned int;

constexpr int NT = 16384;   // tokens
constexpr int NF = 4096;    // features

// fp32 -> bf16 round-to-nearest-even
DI unsigned short f2bf(float f) {
  union { float f; unsigned u; } v; v.f = f;
  unsigned u = v.u;
  u += 0x7fffu + ((u >> 16) & 1u);
  return (unsigned short)(u >> 16);
}

// ---------------- prep: factor transpose + bf16 cast (verified r1) ----------------
// f0 [b][c][d] f32 -> f0s [d][b][c] bf16 ; f1 [a][b][c] f32 -> f1s bf16 (same layout)
__global__ void ks_prep(const float* __restrict__ f0, const float* __restrict__ f1,
                        unsigned short* __restrict__ f0s, unsigned short* __restrict__ f1s) {
  int tid = blockIdx.x * 256 + threadIdx.x;     // grid covers 2*262144
  if (tid < 262144) {
    int d = tid & 63, c = (tid >> 6) & 63, b = tid >> 12;
    f0s[d * 4096 + b * 64 + c] = f2bf(f0[tid]);
  } else {
    int t2 = tid - 262144;
    f1s[t2] = f2bf(f1[t2]);
  }
}

// ---------------- fused: both factors, y kept in LDS ----------------
// block: 8 tokens, all 4096 features. 512 threads = 8 waves.
// LDS: Y [64 a][8 t][64 c2] bf16 (64KB, 16B-XOR-swizzled) + Xq [32 d][8 t][32 c] bf16 (16KB)
__global__ __launch_bounds__(512, 4) void ks_fused(
    const float* __restrict__ x, const unsigned short* __restrict__ f0s,
    const unsigned short* __restrict__ f1s, const float* __restrict__ bias,
    float* __restrict__ out)
{
  __shared__ __align__(16) char L[81920];
  char* Yb = L;                 // [0, 65536)
  char* Xb = L + 65536;         // [65536, 81920)

  const int tid = threadIdx.x;
  const long t0 = (long)blockIdx.x * 8;

  // staging coords: thread -> (token, c-quad, d-quad within half)
  const int st  = tid >> 6;          // 0..7
  const int sco = (tid >> 3) & 7;    // 0..7  (4 c's each)
  const int sdq = tid & 7;           // 0..7  (4 d's each)

  // wave/MFMA coords
  const int lane = tid & 63, wv = tid >> 6;
  const int l15 = lane & 15, lq = lane >> 4;
  const int bt = wv & 3, dsub = wv >> 2;       // wave -> (b-tile, d-subhalf)
  const int tr = l15 & 7;                      // A-row read (rows 8-15 duplicate 0-7)
  const int kxr = (lq * 16) ^ ((tr & 3) << 4); // X-row swizzled chunk offset

  f32x4 v0, v1, v2, v3;
  const float* xb = x + t0 * NF + st * NF;

  // issue 4 full-cacheline-clean loads for quarter (dh, ch) into registers
  auto issue = [&](int dh, int ch) {
    const float* p = xb + (ch * 32 + sco * 4) * 64 + dh * 32 + sdq * 4;
    v0 = *(const f32x4*)(p);
    v1 = *(const f32x4*)(p + 64);
    v2 = *(const f32x4*)(p + 128);
    v3 = *(const f32x4*)(p + 192);
  };
  // convert + write quarter into Xb: [dloc][t][32c], 8B writes, (t&3) XOR key
  auto writeX = [&] {
    #pragma unroll
    for (int j = 0; j < 4; ++j) {
      int dloc = sdq * 4 + j;
      unsigned lo = (unsigned)f2bf(v0[j]) | ((unsigned)f2bf(v1[j]) << 16);
      unsigned hi = (unsigned)f2bf(v2[j]) | ((unsigned)f2bf(v3[j]) << 16);
      u32x2 w{lo, hi};
      *(u32x2*)(Xb + dloc * 512 + st * 64 + ((sco * 8) ^ ((st & 3) << 4))) = w;
    }
  };

  f32x4 acc[16];
  issue(0, 0);

  #pragma unroll
  for (int q = 0; q < 4; ++q) {
    const int dh = q >> 1, ch = q & 1;
    writeX();
    if (q < 3) issue((q + 1) >> 1, (q + 1) & 1);
    __syncthreads();

    // stage1 MFMA: this wave: 16 d-planes (dsub half), b-tile bt, K-half ch
    #pragma unroll
    for (int dd = 0; dd < 16; ++dd) {
      const int dloc = dsub * 16 + dd;
      bf16x8 a = *(const bf16x8*)(Xb + dloc * 512 + tr * 64 + kxr);
      const unsigned short* fp = f0s + (size_t)(dh * 32 + dloc) * 4096
                               + (size_t)(bt * 16 + l15) * 64 + ch * 32 + lq * 8;
      bf16x8 b = *(const bf16x8*)fp;
      if (ch == 0)
        acc[dd] = __builtin_amdgcn_mfma_f32_16x16x32_bf16(a, b, (f32x4){0.f,0.f,0.f,0.f}, 0, 0, 0);
      else
        acc[dd] = __builtin_amdgcn_mfma_f32_16x16x32_bf16(a, b, acc[dd], 0, 0, 0);
    }

    // after K complete (ch==1): write y-slice (16 consecutive c2) into Y
    if (ch == 1 && lq < 2) {
      const int b = bt * 16 + l15;
      const int key = ((b & 7) ^ (lq << 1)) << 4;
      #pragma unroll
      for (int i = 0; i < 4; ++i) {
        const int t = lq * 4 + i;
        u32x4 wA, wB;
        #pragma unroll
        for (int m = 0; m < 4; ++m) {
          wA[m] = (unsigned)f2bf(acc[2*m][i])     | ((unsigned)f2bf(acc[2*m+1][i]) << 16);
          wB[m] = (unsigned)f2bf(acc[8+2*m][i])   | ((unsigned)f2bf(acc[9+2*m][i]) << 16);
        }
        char* yp = Yb + b * 1024 + t * 128;
        *(u32x4*)(yp + ((dh * 64 + dsub * 32 +  0) ^ key)) = wA;
        *(u32x4*)(yp + ((dh * 64 + dsub * 32 + 16) ^ key)) = wB;
      }
    }
    __syncthreads();
  }

  // ---------------- stage2: z[t][a*64+b2] = sum_c2 y[t][a][c2] f1[a][b2][c2] + bias
  #pragma unroll 2
  for (int ai = 0; ai < 8; ++ai) {
    const int a = wv * 8 + ai;
    const int key = ((a & 7) ^ ((tr >> 2) << 1)) << 4;
    const char* yp = Yb + a * 1024 + tr * 128;
    bf16x8 A0 = *(const bf16x8*)(yp + ((     lq * 16) ^ key));
    bf16x8 A1 = *(const bf16x8*)(yp + ((64 + lq * 16) ^ key));
    const unsigned short* fp = f1s + (size_t)a * 4096 + (size_t)l15 * 64 + lq * 8;
    #pragma unroll
    for (int btt = 0; btt < 4; ++btt) {
      bf16x8 B0 = *(const bf16x8*)(fp + btt * 1024);
      bf16x8 B1 = *(const bf16x8*)(fp + btt * 1024 + 32);
      f32x4 acc2 = __builtin_amdgcn_mfma_f32_16x16x32_bf16(A0, B0, (f32x4){0.f,0.f,0.f,0.f}, 0, 0, 0);
      acc2 = __builtin_amdgcn_mfma_f32_16x16x32_bf16(A1, B1, acc2, 0, 0, 0);
      if (lq < 2) {
        const float bv = bias[a * 64 + btt * 16 + l15];
        float* op = out + (t0 + lq * 4) * NF + a * 64 + btt * 16 + l15;
        #pragma unroll
        for (int i = 0; i < 4; ++i) op[(size_t)i * NF] = acc2[i] + bv;
      }
    }
  }
}

// ---------------- naive fp32 fallback (only if workspace too small) ----------------
__global__ void ks_naive(const float* __restrict__ x, const float* __restrict__ f0,
                         const float* __restrict__ f1, const float* __restrict__ bias,
                         float* __restrict__ out)
{
  __shared__ float xr[4096];
  __shared__ float yr[4096];
  long t = blockIdx.x;
  int tid = threadIdx.x;
  for (int i = tid; i < 4096; i += 256) xr[i] = x[t * 4096 + i];
  __syncthreads();
  for (int i = tid; i < 4096; i += 256) {
    int b = i >> 6, d = i & 63;
    float s = 0.f;
    for (int c = 0; c < 64; ++c) s += xr[c * 64 + d] * f0[(b * 64 + c) * 64 + d];
    yr[i] = s;
  }
  __syncthreads();
  for (int i = tid; i < 4096; i += 256) {
    int a = i >> 6;
    float s = bias[i];
    for (int c = 0; c < 64; ++c) s += yr[a * 64 + c] * f1[(size_t)i * 64 + c];
    out[t * 4096 + i] = s;
  }
}

extern "C" void kernel_launch(void* const* d_in, const int* in_sizes, int n_in,
                              void* d_out, int out_size, void* d_ws, size_t ws_size,
                              hipStream_t stream) {
  const float* x    = (const float*)d_in[0];
  const float* f0   = (const float*)d_in[1];
  const float* f1   = (const float*)d_in[2];
  const float* bias = (const float*)d_in[3];
  float* out = (float*)d_out;

  const size_t fbytes = (size_t)64 * 64 * 64 * 2;     // 512 KB per factor
  if (ws_size >= 2 * fbytes) {
    unsigned short* f0s = (unsigned short*)d_ws;
    unsigned short* f1s = f0s + 64 * 64 * 64;
    ks_prep<<<2048, 256, 0, stream>>>(f0, f1, f0s, f1s);
    ks_fused<<<NT / 8, 512, 0, stream>>>(x, f0s, f1s, bias, out);
  } else {
    ks_naive<<<NT, 256, 0, stream>>>(x, f0, f1, bias, out);
  }
}

// Round 4
// 274.935 us; speedup vs baseline: 1.3741x; 1.3741x over previous
//
#include <hip/hip_runtime.h>
#include <cstdint>
#include <cstddef>

#define DI __device__ __forceinline__

using f32x4  = __attribute__((ext_vector_type(4))) float;
using bf16x8 = __attribute__((ext_vector_type(8))) short;
using u32x2  = __attribute__((ext_vector_type(2))) unsigned int;
using u32x4  = __attribute__((ext_vector_type(4))) unsigned int;

constexpr int NT = 16384;   // tokens
constexpr int NF = 4096;    // features

// fp32 -> bf16 round-to-nearest-even
DI unsigned short f2bf(float f) {
  union { float f; unsigned u; } v; v.f = f;
  unsigned u = v.u;
  u += 0x7fffu + ((u >> 16) & 1u);
  return (unsigned short)(u >> 16);
}

// ---------------- prep: factor transpose + bf16 cast (verified r2) ----------------
// f0 [b][c][d] f32 -> f0s [d][b][c] bf16 ; f1 [a][b][c] f32 -> f1s bf16 (same layout)
__global__ void ks_prep(const float* __restrict__ f0, const float* __restrict__ f1,
                        unsigned short* __restrict__ f0s, unsigned short* __restrict__ f1s) {
  int tid = blockIdx.x * 256 + threadIdx.x;     // grid covers 2*262144
  if (tid < 262144) {
    int d = tid & 63, c = (tid >> 6) & 63, b = tid >> 12;
    f0s[d * 4096 + b * 64 + c] = f2bf(f0[tid]);
  } else {
    int t2 = tid - 262144;
    f1s[t2] = f2bf(f1[t2]);
  }
}

// ---------------- stage 1 v3 ----------------
// block: 128 tokens x 8 d-planes (wave wv owns d = dg*8+wv, f0 slice persistent in regs).
// y' layout: element = t*4096 + dg*512 + b*8 + dloc   (d-minor 16B chunks for stage2)
// grid 1024, mapped so the 8 dg-siblings of a token tile share an XCD.
__global__ __launch_bounds__(512, 4) void ks1(
    const float* __restrict__ x, const unsigned short* __restrict__ f0s,
    unsigned short* __restrict__ yp)
{
  // LDS: X dbuf 2x16KB (bf16 [8d][16t][64c], XOR-swizzled) + Ybuf dbuf 2x16.25KB
  __shared__ __align__(16) char L[32768 + 2 * 16640];
  char* const Xb0 = L;
  char* const Xb1 = L + 16384;
  char* const Yb0 = L + 32768;
  char* const Yb1 = L + 32768 + 16640;

  const int w  = blockIdx.x;
  const int tt = (w & 7) | ((w >> 6) << 3);   // 0..127 ; siblings (dg 0..7) share XCD
  const int dg = (w >> 3) & 7;
  const long T0 = (long)tt * 128;

  const int tid = threadIdx.x, lane = tid & 63, wv = tid >> 6;
  const int l15 = lane & 15, lq = lane >> 4;
  const int d = dg * 8 + wv;

  // persistent A-frags: f0s[d][b][c], loaded once (32 VGPR)
  bf16x8 fA[4][2];
  #pragma unroll
  for (int bt = 0; bt < 4; ++bt)
    #pragma unroll
    for (int kh = 0; kh < 2; ++kh)
      fA[bt][kh] = *(const bf16x8*)(f0s + (size_t)d * 4096 + (bt * 16 + l15) * 64 + kh * 32 + lq * 8);

  // x staging map: thread -> (t within subtile, c0 quad, d-quad)
  const int st_t = tid >> 5, st_c0 = (tid >> 1) & 15, st_dq = tid & 1;
  const float* const xrow0 = x + (T0 + st_t) * (long)NF + dg * 8 + st_dq * 4;
  const int wkey = (st_t & 7) << 4;

  f32x4 r0, r1, r2, r3;
  auto issue = [&](int st) {
    const float* p = xrow0 + (long)st * 16 * NF + st_c0 * 4 * 64;
    r0 = *(const f32x4*)(p);
    r1 = *(const f32x4*)(p + 64);
    r2 = *(const f32x4*)(p + 128);
    r3 = *(const f32x4*)(p + 192);
  };
  auto stageX = [&](char* X) {
    #pragma unroll
    for (int e = 0; e < 4; ++e) {
      int p = st_dq * 4 + e;
      unsigned lo = (unsigned)f2bf(r0[e]) | ((unsigned)f2bf(r1[e]) << 16);
      unsigned hi = (unsigned)f2bf(r2[e]) | ((unsigned)f2bf(r3[e]) << 16);
      *(u32x2*)(X + p * 2048 + st_t * 128 + ((st_c0 * 8) ^ wkey)) = u32x2{lo, hi};
    }
  };

  issue(0);
  stageX(Xb0);          // waits on issue(0) loads only
  issue(1);             // in flight across the barrier
  __syncthreads();

  const int rkey = (l15 & 7) << 4;

  for (int st = 0; st < 8; ++st) {
    char* const Xc = (st & 1) ? Xb1 : Xb0;
    char* const Xn = (st & 1) ? Xb0 : Xb1;
    char* const Yc = (st & 1) ? Yb1 : Yb0;

    // ---- MFMA: A = f0 (persistent), B = x from LDS ----
    const char* Xs = Xc + wv * 2048 + l15 * 128;
    bf16x8 bx0 = *(const bf16x8*)(Xs + ((0  + lq * 16) ^ rkey));
    bf16x8 bx1 = *(const bf16x8*)(Xs + ((64 + lq * 16) ^ rkey));
    f32x4 acc[4];
    #pragma unroll
    for (int bt = 0; bt < 4; ++bt) {
      acc[bt] = __builtin_amdgcn_mfma_f32_16x16x32_bf16(fA[bt][0], bx0, (f32x4){0.f,0.f,0.f,0.f}, 0, 0, 0);
      acc[bt] = __builtin_amdgcn_mfma_f32_16x16x32_bf16(fA[bt][1], bx1, acc[bt], 0, 0, 0);
    }

    // ---- Ybuf write: [16 t][stride 1040][b*16B + dloc*2B]; D: row=b(lq*4+i), col=t(l15)
    {
      char* Yw = Yc + l15 * 1040 + wv * 2;
      #pragma unroll
      for (int bt = 0; bt < 4; ++bt)
        #pragma unroll
        for (int i = 0; i < 4; ++i)
          *(unsigned short*)(Yw + (bt * 16 + lq * 4 + i) * 16) = f2bf(acc[bt][i]);
    }

    // ---- stage next X subtile + issue next loads (stay in flight over barrier) ----
    stageX(Xn);
    issue(st + 2 <= 7 ? st + 2 : 7);
    __syncthreads();

    // ---- copy Ybuf -> y' (1KB contiguous per warp) ----
    {
      const char* Yr = Yc;
      #pragma unroll
      for (int h = 0; h < 2; ++h) {
        int t = (tid >> 6) + h * 8;
        int c16 = tid & 63;
        u32x4 v = *(const u32x4*)(Yr + t * 1040 + c16 * 16);
        *(u32x4*)(yp + (T0 + st * 16 + t) * (size_t)NF + dg * 512 + c16 * 8) = v;
      }
    }
  }
}

// ---------------- stage 2 v3 ----------------
// block: 16 tokens, 256 threads = 4 waves (bh, ah). No LDS, no barriers.
// z[t][a*64+b2] = sum_c2 y[t][a][c2] * f1[a][b2][c2] + bias
__global__ __launch_bounds__(256, 4) void ks2(
    const unsigned short* __restrict__ yp, const unsigned short* __restrict__ f1s,
    const float* __restrict__ bias, float* __restrict__ out)
{
  const long T0 = (long)blockIdx.x * 16;
  const int tid = threadIdx.x, lane = tid & 63, wv = tid >> 6;
  const int l15 = lane & 15, lq = lane >> 4;
  const int bh = wv >> 1, ah = wv & 1;

  const unsigned short* const ybase = yp + (T0 + l15) * (size_t)NF + lq * 512; // +kh*2048 +a*8
  const unsigned short* const fbase = f1s + (size_t)(bh * 32 + l15) * 64 + lq * 8; // +a*4096 +bt*1024 +kh*32
  const float* const bbase = bias + bh * 32 + lq * 4;                          // +a*64 +bt*16
  float* const obase = out + (T0 + l15) * (size_t)NF + bh * 32 + lq * 4;       // +a*64 +bt*16

  struct F { bf16x8 by0, by1, fa00, fa01, fa10, fa11; f32x4 bv0, bv1; };
  auto fetch = [&](int a, F& f) {
    f.by0 = *(const bf16x8*)(ybase + (size_t)a * 8);
    f.by1 = *(const bf16x8*)(ybase + 2048 + (size_t)a * 8);
    const unsigned short* fp = fbase + (size_t)a * 4096;
    f.fa00 = *(const bf16x8*)(fp);
    f.fa01 = *(const bf16x8*)(fp + 32);
    f.fa10 = *(const bf16x8*)(fp + 1024);
    f.fa11 = *(const bf16x8*)(fp + 1024 + 32);
    f.bv0 = *(const f32x4*)(bbase + a * 64);
    f.bv1 = *(const f32x4*)(bbase + a * 64 + 16);
  };
  auto work = [&](int a, const F& f) {
    f32x4 acc0 = __builtin_amdgcn_mfma_f32_16x16x32_bf16(f.fa00, f.by0, (f32x4){0.f,0.f,0.f,0.f}, 0, 0, 0);
    acc0 = __builtin_amdgcn_mfma_f32_16x16x32_bf16(f.fa01, f.by1, acc0, 0, 0, 0);
    f32x4 acc1 = __builtin_amdgcn_mfma_f32_16x16x32_bf16(f.fa10, f.by0, (f32x4){0.f,0.f,0.f,0.f}, 0, 0, 0);
    acc1 = __builtin_amdgcn_mfma_f32_16x16x32_bf16(f.fa11, f.by1, acc1, 0, 0, 0);
    *(f32x4*)(obase + (size_t)a * 64)      = acc0 + f.bv0;   // D: row=b2(lq*4+i), col=t(l15)
    *(f32x4*)(obase + (size_t)a * 64 + 16) = acc1 + f.bv1;
  };

  const int a0 = ah * 32;
  F fA_, fB_;
  fetch(a0, fA_);
  #pragma unroll 4
  for (int i = 0; i < 32; i += 2) {
    if (i + 1 < 32) fetch(a0 + i + 1, fB_);
    work(a0 + i, fA_);
    if (i + 2 < 32) fetch(a0 + i + 2, fA_);
    if (i + 1 < 32) work(a0 + i + 1, fB_);
  }
}

// ---------------- naive fp32 fallback (only if workspace too small) ----------------
__global__ void ks_naive(const float* __restrict__ x, const float* __restrict__ f0,
                         const float* __restrict__ f1, const float* __restrict__ bias,
                         float* __restrict__ out)
{
  __shared__ float xr[4096];
  __shared__ float yr[4096];
  long t = blockIdx.x;
  int tid = threadIdx.x;
  for (int i = tid; i < 4096; i += 256) xr[i] = x[t * 4096 + i];
  __syncthreads();
  for (int i = tid; i < 4096; i += 256) {
    int b = i >> 6, d = i & 63;
    float s = 0.f;
    for (int c = 0; c < 64; ++c) s += xr[c * 64 + d] * f0[(b * 64 + c) * 64 + d];
    yr[i] = s;
  }
  __syncthreads();
  for (int i = tid; i < 4096; i += 256) {
    int a = i >> 6;
    float s = bias[i];
    for (int c = 0; c < 64; ++c) s += yr[a * 64 + c] * f1[(size_t)i * 64 + c];
    out[t * 4096 + i] = s;
  }
}

extern "C" void kernel_launch(void* const* d_in, const int* in_sizes, int n_in,
                              void* d_out, int out_size, void* d_ws, size_t ws_size,
                              hipStream_t stream) {
  const float* x    = (const float*)d_in[0];
  const float* f0   = (const float*)d_in[1];
  const float* f1   = (const float*)d_in[2];
  const float* bias = (const float*)d_in[3];
  float* out = (float*)d_out;

  const size_t ybytes = (size_t)NT * NF * 2;          // 128 MB bf16 intermediate (y')
  const size_t fbytes = (size_t)64 * 64 * 64 * 2;     // 512 KB per factor
  if (ws_size >= ybytes + 2 * fbytes) {
    unsigned short* yw  = (unsigned short*)d_ws;
    unsigned short* f0s = yw + (size_t)NT * NF;
    unsigned short* f1s = f0s + 64 * 64 * 64;
    ks_prep<<<2048, 256, 0, stream>>>(f0, f1, f0s, f1s);
    ks1<<<1024, 512, 0, stream>>>(x, f0s, yw);
    ks2<<<NT / 16, 256, 0, stream>>>(yw, f1s, bias, out);
  } else {
    ks_naive<<<NT, 256, 0, stream>>>(x, f0, f1, bias, out);
  }
}

// Round 5
// 238.896 us; speedup vs baseline: 1.5814x; 1.1509x over previous
//
#include <hip/hip_runtime.h>
#include <cstdint>
#include <cstddef>

#define DI __device__ __forceinline__

using f32x4  = __attribute__((ext_vector_type(4))) float;
using bf16x8 = __attribute__((ext_vector_type(8))) short;
using u32x2  = __attribute__((ext_vector_type(2))) unsigned int;
using u32x4  = __attribute__((ext_vector_type(4))) unsigned int;

constexpr int NT = 16384;   // tokens
constexpr int NF = 4096;    // features

// fp32 -> bf16 round-to-nearest-even
DI unsigned short f2bf(float f) {
  union { float f; unsigned u; } v; v.f = f;
  unsigned u = v.u;
  u += 0x7fffu + ((u >> 16) & 1u);
  return (unsigned short)(u >> 16);
}

// ---------------- prep: factor transpose + bf16 cast (verified r2) ----------------
// f0 [b][c][d] f32 -> f0s [d][b][c] bf16 ; f1 [a][b][c] f32 -> f1s bf16 (same layout)
__global__ void ks_prep(const float* __restrict__ f0, const float* __restrict__ f1,
                        unsigned short* __restrict__ f0s, unsigned short* __restrict__ f1s) {
  int tid = blockIdx.x * 256 + threadIdx.x;     // grid covers 2*262144
  if (tid < 262144) {
    int d = tid & 63, c = (tid >> 6) & 63, b = tid >> 12;
    f0s[d * 4096 + b * 64 + c] = f2bf(f0[tid]);
  } else {
    int t2 = tid - 262144;
    f1s[t2] = f2bf(f1[t2]);
  }
}

// ---------------- stage 1 (verified r4, unchanged) ----------------
// block: 128 tokens x 8 d-planes (wave wv owns d = dg*8+wv, f0 slice persistent in regs).
// y' layout: element = t*4096 + dg*512 + b*8 + dloc   (d-minor 16B chunks for stage2)
__global__ __launch_bounds__(512, 4) void ks1(
    const float* __restrict__ x, const unsigned short* __restrict__ f0s,
    unsigned short* __restrict__ yp)
{
  __shared__ __align__(16) char L[32768 + 2 * 16640];
  char* const Xb0 = L;
  char* const Xb1 = L + 16384;
  char* const Yb0 = L + 32768;
  char* const Yb1 = L + 32768 + 16640;

  const int w  = blockIdx.x;
  const int tt = (w & 7) | ((w >> 6) << 3);   // siblings (dg 0..7) share XCD
  const int dg = (w >> 3) & 7;
  const long T0 = (long)tt * 128;

  const int tid = threadIdx.x, lane = tid & 63, wv = tid >> 6;
  const int l15 = lane & 15, lq = lane >> 4;
  const int d = dg * 8 + wv;

  bf16x8 fA[4][2];
  #pragma unroll
  for (int bt = 0; bt < 4; ++bt)
    #pragma unroll
    for (int kh = 0; kh < 2; ++kh)
      fA[bt][kh] = *(const bf16x8*)(f0s + (size_t)d * 4096 + (bt * 16 + l15) * 64 + kh * 32 + lq * 8);

  const int st_t = tid >> 5, st_c0 = (tid >> 1) & 15, st_dq = tid & 1;
  const float* const xrow0 = x + (T0 + st_t) * (long)NF + dg * 8 + st_dq * 4;
  const int wkey = (st_t & 7) << 4;

  f32x4 r0, r1, r2, r3;
  auto issue = [&](int st) {
    const float* p = xrow0 + (long)st * 16 * NF + st_c0 * 4 * 64;
    r0 = *(const f32x4*)(p);
    r1 = *(const f32x4*)(p + 64);
    r2 = *(const f32x4*)(p + 128);
    r3 = *(const f32x4*)(p + 192);
  };
  auto stageX = [&](char* X) {
    #pragma unroll
    for (int e = 0; e < 4; ++e) {
      int p = st_dq * 4 + e;
      unsigned lo = (unsigned)f2bf(r0[e]) | ((unsigned)f2bf(r1[e]) << 16);
      unsigned hi = (unsigned)f2bf(r2[e]) | ((unsigned)f2bf(r3[e]) << 16);
      *(u32x2*)(X + p * 2048 + st_t * 128 + ((st_c0 * 8) ^ wkey)) = u32x2{lo, hi};
    }
  };

  issue(0);
  stageX(Xb0);
  issue(1);
  __syncthreads();

  const int rkey = (l15 & 7) << 4;

  for (int st = 0; st < 8; ++st) {
    char* const Xc = (st & 1) ? Xb1 : Xb0;
    char* const Xn = (st & 1) ? Xb0 : Xb1;
    char* const Yc = (st & 1) ? Yb1 : Yb0;

    const char* Xs = Xc + wv * 2048 + l15 * 128;
    bf16x8 bx0 = *(const bf16x8*)(Xs + ((0  + lq * 16) ^ rkey));
    bf16x8 bx1 = *(const bf16x8*)(Xs + ((64 + lq * 16) ^ rkey));
    f32x4 acc[4];
    #pragma unroll
    for (int bt = 0; bt < 4; ++bt) {
      acc[bt] = __builtin_amdgcn_mfma_f32_16x16x32_bf16(fA[bt][0], bx0, (f32x4){0.f,0.f,0.f,0.f}, 0, 0, 0);
      acc[bt] = __builtin_amdgcn_mfma_f32_16x16x32_bf16(fA[bt][1], bx1, acc[bt], 0, 0, 0);
    }

    {
      char* Yw = Yc + l15 * 1040 + wv * 2;
      #pragma unroll
      for (int bt = 0; bt < 4; ++bt)
        #pragma unroll
        for (int i = 0; i < 4; ++i)
          *(unsigned short*)(Yw + (bt * 16 + lq * 4 + i) * 16) = f2bf(acc[bt][i]);
    }

    stageX(Xn);
    issue(st + 2 <= 7 ? st + 2 : 7);
    __syncthreads();

    {
      const char* Yr = Yc;
      #pragma unroll
      for (int h = 0; h < 2; ++h) {
        int t = (tid >> 6) + h * 8;
        int c16 = tid & 63;
        u32x4 v = *(const u32x4*)(Yr + t * 1040 + c16 * 16);
        *(u32x4*)(yp + (T0 + st * 16 + t) * (size_t)NF + dg * 512 + c16 * 8) = v;
      }
    }
  }
}

// ---------------- stage 2 v4: per-a block-GEMM, f1 persistent in regs ----------------
// block: 512 thr = 8 waves; wave wv owns a = ag*8+wv, streams 128 tokens (8 tiles of 16).
// The 8 waves read adjacent 16B chunks of each y' line (full-line consumption).
__global__ __launch_bounds__(512, 4) void ks2(
    const unsigned short* __restrict__ yp, const unsigned short* __restrict__ f1s,
    const float* __restrict__ bias, float* __restrict__ out)
{
  const int bid = blockIdx.x;
  const int ag  = bid & 7;
  const long T0 = (long)(bid >> 3) * 128;

  const int tid = threadIdx.x, lane = tid & 63, wv = tid >> 6;
  const int l15 = lane & 15, lq = lane >> 4;
  const int a = ag * 8 + wv;

  // persistent A operand: f1[a][b2][c2], 8 frags = 32 VGPR
  bf16x8 fa[4][2];
  #pragma unroll
  for (int bt = 0; bt < 4; ++bt)
    #pragma unroll
    for (int kh = 0; kh < 2; ++kh)
      fa[bt][kh] = *(const bf16x8*)(f1s + (size_t)a * 4096 + (bt * 16 + l15) * 64 + kh * 32 + lq * 8);
  f32x4 bv[4];
  #pragma unroll
  for (int bt = 0; bt < 4; ++bt)
    bv[bt] = *(const f32x4*)(bias + a * 64 + bt * 16 + lq * 4);

  // B operand stream: y'[t][lq*512 + a*8 .. +7] (+2048 for k-half 1)
  const unsigned short* const yb = yp + (T0 + l15) * (size_t)NF + lq * 512 + a * 8;
  float* const ob = out + (T0 + l15) * (size_t)NF + a * 64 + lq * 4;

  // depth-2 software pipeline over 8 tiles (16 tokens each; tile stride = 16*4096 elems)
  bf16x8 c0 = *(const bf16x8*)(yb);
  bf16x8 c1 = *(const bf16x8*)(yb + 2048);
  bf16x8 p0 = *(const bf16x8*)(yb + 65536);
  bf16x8 p1 = *(const bf16x8*)(yb + 65536 + 2048);

  #pragma unroll
  for (int t8 = 0; t8 < 8; ++t8) {
    bf16x8 q0 = p0, q1 = p1;
    if (t8 < 6) {
      q0 = *(const bf16x8*)(yb + (t8 + 2) * 65536);
      q1 = *(const bf16x8*)(yb + (t8 + 2) * 65536 + 2048);
    }
    f32x4 acc[4];
    #pragma unroll
    for (int bt = 0; bt < 4; ++bt) {
      acc[bt] = __builtin_amdgcn_mfma_f32_16x16x32_bf16(fa[bt][0], c0, (f32x4){0.f,0.f,0.f,0.f}, 0, 0, 0);
      acc[bt] = __builtin_amdgcn_mfma_f32_16x16x32_bf16(fa[bt][1], c1, acc[bt], 0, 0, 0);
    }
    float* op = ob + (size_t)t8 * 16 * NF;
    #pragma unroll
    for (int bt = 0; bt < 4; ++bt)
      *(f32x4*)(op + bt * 16) = acc[bt] + bv[bt];
    c0 = p0; c1 = p1;
    p0 = q0; p1 = q1;
  }
}

// ---------------- naive fp32 fallback (only if workspace too small) ----------------
__global__ void ks_naive(const float* __restrict__ x, const float* __restrict__ f0,
                         const float* __restrict__ f1, const float* __restrict__ bias,
                         float* __restrict__ out)
{
  __shared__ float xr[4096];
  __shared__ float yr[4096];
  long t = blockIdx.x;
  int tid = threadIdx.x;
  for (int i = tid; i < 4096; i += 256) xr[i] = x[t * 4096 + i];
  __syncthreads();
  for (int i = tid; i < 4096; i += 256) {
    int b = i >> 6, d = i & 63;
    float s = 0.f;
    for (int c = 0; c < 64; ++c) s += xr[c * 64 + d] * f0[(b * 64 + c) * 64 + d];
    yr[i] = s;
  }
  __syncthreads();
  for (int i = tid; i < 4096; i += 256) {
    int a = i >> 6;
    float s = bias[i];
    for (int c = 0; c < 64; ++c) s += yr[a * 64 + c] * f1[(size_t)i * 64 + c];
    out[t * 4096 + i] = s;
  }
}

extern "C" void kernel_launch(void* const* d_in, const int* in_sizes, int n_in,
                              void* d_out, int out_size, void* d_ws, size_t ws_size,
                              hipStream_t stream) {
  const float* x    = (const float*)d_in[0];
  const float* f0   = (const float*)d_in[1];
  const float* f1   = (const float*)d_in[2];
  const float* bias = (const float*)d_in[3];
  float* out = (float*)d_out;

  const size_t ybytes = (size_t)NT * NF * 2;          // 128 MB bf16 intermediate (y')
  const size_t fbytes = (size_t)64 * 64 * 64 * 2;     // 512 KB per factor
  if (ws_size >= ybytes + 2 * fbytes) {
    unsigned short* yw  = (unsigned short*)d_ws;
    unsigned short* f0s = yw + (size_t)NT * NF;
    unsigned short* f1s = f0s + 64 * 64 * 64;
    ks_prep<<<2048, 256, 0, stream>>>(f0, f1, f0s, f1s);
    ks1<<<1024, 512, 0, stream>>>(x, f0s, yw);
    ks2<<<1024, 512, 0, stream>>>(yw, f1s, bias, out);
  } else {
    ks_naive<<<NT, 256, 0, stream>>>(x, f0, f1, bias, out);
  }
}

// Round 6
// 206.930 us; speedup vs baseline: 1.8257x; 1.1545x over previous
//
#include <hip/hip_runtime.h>
#include <cstdint>
#include <cstddef>

#define DI __device__ __forceinline__

using f32x4  = __attribute__((ext_vector_type(4))) float;
using bf16x8 = __attribute__((ext_vector_type(8))) short;
using u32x2  = __attribute__((ext_vector_type(2))) unsigned int;
using u32x4  = __attribute__((ext_vector_type(4))) unsigned int;

constexpr int NT = 16384;   // tokens
constexpr int NF = 4096;    // features

// fp32 -> bf16 round-to-nearest-even
DI unsigned short f2bf(float f) {
  union { float f; unsigned u; } v; v.f = f;
  unsigned u = v.u;
  u += 0x7fffu + ((u >> 16) & 1u);
  return (unsigned short)(u >> 16);
}

// async global->LDS, 16B per lane. lds dst is wave-uniform base; HW adds lane*16.
DI void gload_lds16(const void* g, void* l) {
  __builtin_amdgcn_global_load_lds(
      (const __attribute__((address_space(1))) unsigned int*)g,
      (__attribute__((address_space(3))) unsigned int*)l, 16, 0, 0);
}

// ---------------- prep: factor transpose + bf16 cast (verified r2) ----------------
// f0 [b][c][d] f32 -> f0s [d][b][c] bf16 ; f1 [a][b][c] f32 -> f1s bf16 (same layout)
__global__ void ks_prep(const float* __restrict__ f0, const float* __restrict__ f1,
                        unsigned short* __restrict__ f0s, unsigned short* __restrict__ f1s) {
  int tid = blockIdx.x * 256 + threadIdx.x;     // grid covers 2*262144
  if (tid < 262144) {
    int d = tid & 63, c = (tid >> 6) & 63, b = tid >> 12;
    f0s[d * 4096 + b * 64 + c] = f2bf(f0[tid]);
  } else {
    int t2 = tid - 262144;
    f1s[t2] = f2bf(f1[t2]);
  }
}

// ---------------- stage 1 (verified r4, unchanged) ----------------
// block: 128 tokens x 8 d-planes (wave wv owns d = dg*8+wv, f0 slice persistent in regs).
// y' layout: element = t*4096 + dg*512 + b*8 + dloc   (d-minor 16B chunks for stage2)
__global__ __launch_bounds__(512, 4) void ks1(
    const float* __restrict__ x, const unsigned short* __restrict__ f0s,
    unsigned short* __restrict__ yp)
{
  __shared__ __align__(16) char L[32768 + 2 * 16640];
  char* const Xb0 = L;
  char* const Xb1 = L + 16384;
  char* const Yb0 = L + 32768;
  char* const Yb1 = L + 32768 + 16640;

  const int w  = blockIdx.x;
  const int tt = (w & 7) | ((w >> 6) << 3);   // siblings (dg 0..7) share XCD
  const int dg = (w >> 3) & 7;
  const long T0 = (long)tt * 128;

  const int tid = threadIdx.x, lane = tid & 63, wv = tid >> 6;
  const int l15 = lane & 15, lq = lane >> 4;
  const int d = dg * 8 + wv;

  bf16x8 fA[4][2];
  #pragma unroll
  for (int bt = 0; bt < 4; ++bt)
    #pragma unroll
    for (int kh = 0; kh < 2; ++kh)
      fA[bt][kh] = *(const bf16x8*)(f0s + (size_t)d * 4096 + (bt * 16 + l15) * 64 + kh * 32 + lq * 8);

  const int st_t = tid >> 5, st_c0 = (tid >> 1) & 15, st_dq = tid & 1;
  const float* const xrow0 = x + (T0 + st_t) * (long)NF + dg * 8 + st_dq * 4;
  const int wkey = (st_t & 7) << 4;

  f32x4 r0, r1, r2, r3;
  auto issue = [&](int st) {
    const float* p = xrow0 + (long)st * 16 * NF + st_c0 * 4 * 64;
    r0 = *(const f32x4*)(p);
    r1 = *(const f32x4*)(p + 64);
    r2 = *(const f32x4*)(p + 128);
    r3 = *(const f32x4*)(p + 192);
  };
  auto stageX = [&](char* X) {
    #pragma unroll
    for (int e = 0; e < 4; ++e) {
      int p = st_dq * 4 + e;
      unsigned lo = (unsigned)f2bf(r0[e]) | ((unsigned)f2bf(r1[e]) << 16);
      unsigned hi = (unsigned)f2bf(r2[e]) | ((unsigned)f2bf(r3[e]) << 16);
      *(u32x2*)(X + p * 2048 + st_t * 128 + ((st_c0 * 8) ^ wkey)) = u32x2{lo, hi};
    }
  };

  issue(0);
  stageX(Xb0);
  issue(1);
  __syncthreads();

  const int rkey = (l15 & 7) << 4;

  for (int st = 0; st < 8; ++st) {
    char* const Xc = (st & 1) ? Xb1 : Xb0;
    char* const Xn = (st & 1) ? Xb0 : Xb1;
    char* const Yc = (st & 1) ? Yb1 : Yb0;

    const char* Xs = Xc + wv * 2048 + l15 * 128;
    bf16x8 bx0 = *(const bf16x8*)(Xs + ((0  + lq * 16) ^ rkey));
    bf16x8 bx1 = *(const bf16x8*)(Xs + ((64 + lq * 16) ^ rkey));
    f32x4 acc[4];
    #pragma unroll
    for (int bt = 0; bt < 4; ++bt) {
      acc[bt] = __builtin_amdgcn_mfma_f32_16x16x32_bf16(fA[bt][0], bx0, (f32x4){0.f,0.f,0.f,0.f}, 0, 0, 0);
      acc[bt] = __builtin_amdgcn_mfma_f32_16x16x32_bf16(fA[bt][1], bx1, acc[bt], 0, 0, 0);
    }

    {
      char* Yw = Yc + l15 * 1040 + wv * 2;
      #pragma unroll
      for (int bt = 0; bt < 4; ++bt)
        #pragma unroll
        for (int i = 0; i < 4; ++i)
          *(unsigned short*)(Yw + (bt * 16 + lq * 4 + i) * 16) = f2bf(acc[bt][i]);
    }

    stageX(Xn);
    issue(st + 2 <= 7 ? st + 2 : 7);
    __syncthreads();

    {
      const char* Yr = Yc;
      #pragma unroll
      for (int h = 0; h < 2; ++h) {
        int t = (tid >> 6) + h * 8;
        int c16 = tid & 63;
        u32x4 v = *(const u32x4*)(Yr + t * 1040 + c16 * 16);
        *(u32x4*)(yp + (T0 + st * 16 + t) * (size_t)NF + dg * 512 + c16 * 8) = v;
      }
    }
  }
}

// ---------------- stage 2 v5: LDS-staged dense-line reads ----------------
// block: 512 thr = 8 waves; wave wv owns a = ag*8+wv; block streams 256 tokens
// as 8 tiles of 32. Per (t,dg) the block's y' span is a dense 128B run ->
// global_load_lds stages full lines (1KB/instr); dbuf 2x32KB; counted vmcnt(8).
__global__ __launch_bounds__(512, 4) void ks2(
    const unsigned short* __restrict__ yp, const unsigned short* __restrict__ f1s,
    const float* __restrict__ bias, float* __restrict__ out)
{
  __shared__ __align__(16) char Yb[2][32768];   // [buf][32 t][8 dg][128 B]

  const int bid = blockIdx.x;
  const int ag  = bid & 7;
  const long T0 = (long)(bid >> 3) * 256;

  const int tid = threadIdx.x, lane = tid & 63, wv = tid >> 6;
  const int l15 = lane & 15, lq = lane >> 4;
  const int a = ag * 8 + wv;

  // persistent A operand: f1[a][b2][c2] (32 VGPR) + bias (16 VGPR)
  bf16x8 fa[4][2];
  #pragma unroll
  for (int bt = 0; bt < 4; ++bt)
    #pragma unroll
    for (int kh = 0; kh < 2; ++kh)
      fa[bt][kh] = *(const bf16x8*)(f1s + (size_t)a * 4096 + (bt * 16 + l15) * 64 + kh * 32 + lq * 8);
  f32x4 bv[4];
  #pragma unroll
  for (int bt = 0; bt < 4; ++bt)
    bv[bt] = *(const f32x4*)(bias + a * 64 + bt * 16 + lq * 4);

  // stage tile -> buf: wave wv loads rows {wv, 8+wv, 16+wv, 24+wv}; slot s=lane gets
  // global chunk g = s ^ (t&7) (involution; stays within the 128B dg-run -> coalesced)
  auto stage = [&](int tile, int buf) {
    #pragma unroll
    for (int i = 0; i < 4; ++i) {
      const int trow = i * 8 + wv;
      const int g = lane ^ (trow & 7);
      const char* src = (const char*)yp + (T0 + (long)tile * 32 + trow) * 8192
                        + ((g >> 3) << 10) + ag * 128 + (g & 7) * 16;
      gload_lds16(src, &Yb[buf][trow * 1024]);
    }
  };

  stage(0, 0);
  asm volatile("s_waitcnt vmcnt(0)" ::: "memory");
  __syncthreads();

  #pragma unroll
  for (int tile = 0; tile < 8; ++tile) {
    if (tile < 7) stage(tile + 1, (tile + 1) & 1);

    const char* Yt = Yb[tile & 1];
    const int sw = wv ^ (l15 & 7);           // swizzled chunk base (dg added per frag)
    #pragma unroll
    for (int tt = 0; tt < 2; ++tt) {
      const char* Yr = Yt + (tt * 16 + l15) * 1024;
      bf16x8 c0 = *(const bf16x8*)(Yr + ((lq * 8 + sw) * 16));            // dg = lq
      bf16x8 c1 = *(const bf16x8*)(Yr + (((4 + lq) * 8 + sw) * 16));      // dg = 4+lq
      f32x4 acc[4];
      #pragma unroll
      for (int bt = 0; bt < 4; ++bt) {
        acc[bt] = __builtin_amdgcn_mfma_f32_16x16x32_bf16(fa[bt][0], c0, (f32x4){0.f,0.f,0.f,0.f}, 0, 0, 0);
        acc[bt] = __builtin_amdgcn_mfma_f32_16x16x32_bf16(fa[bt][1], c1, acc[bt], 0, 0, 0);
      }
      float* op = out + (T0 + (long)tile * 32 + tt * 16 + l15) * NF + a * 64 + lq * 4;
      #pragma unroll
      for (int bt = 0; bt < 4; ++bt)
        *(f32x4*)(op + bt * 16) = acc[bt] + bv[bt];
    }

    // next-tile loads (oldest 4 outstanding after <=8 stores) must land; stores may lag
    asm volatile("s_waitcnt vmcnt(8)" ::: "memory");
    __syncthreads();
  }
}

// ---------------- naive fp32 fallback (only if workspace too small) ----------------
__global__ void ks_naive(const float* __restrict__ x, const float* __restrict__ f0,
                         const float* __restrict__ f1, const float* __restrict__ bias,
                         float* __restrict__ out)
{
  __shared__ float xr[4096];
  __shared__ float yr[4096];
  long t = blockIdx.x;
  int tid = threadIdx.x;
  for (int i = tid; i < 4096; i += 256) xr[i] = x[t * 4096 + i];
  __syncthreads();
  for (int i = tid; i < 4096; i += 256) {
    int b = i >> 6, d = i & 63;
    float s = 0.f;
    for (int c = 0; c < 64; ++c) s += xr[c * 64 + d] * f0[(b * 64 + c) * 64 + d];
    yr[i] = s;
  }
  __syncthreads();
  for (int i = tid; i < 4096; i += 256) {
    int a = i >> 6;
    float s = bias[i];
    for (int c = 0; c < 64; ++c) s += yr[a * 64 + c] * f1[(size_t)i * 64 + c];
    out[t * 4096 + i] = s;
  }
}

extern "C" void kernel_launch(void* const* d_in, const int* in_sizes, int n_in,
                              void* d_out, int out_size, void* d_ws, size_t ws_size,
                              hipStream_t stream) {
  const float* x    = (const float*)d_in[0];
  const float* f0   = (const float*)d_in[1];
  const float* f1   = (const float*)d_in[2];
  const float* bias = (const float*)d_in[3];
  float* out = (float*)d_out;

  const size_t ybytes = (size_t)NT * NF * 2;          // 128 MB bf16 intermediate (y')
  const size_t fbytes = (size_t)64 * 64 * 64 * 2;     // 512 KB per factor
  if (ws_size >= ybytes + 2 * fbytes) {
    unsigned short* yw  = (unsigned short*)d_ws;
    unsigned short* f0s = yw + (size_t)NT * NF;
    unsigned short* f1s = f0s + 64 * 64 * 64;
    ks_prep<<<2048, 256, 0, stream>>>(f0, f1, f0s, f1s);
    ks1<<<1024, 512, 0, stream>>>(x, f0s, yw);
    ks2<<<512, 512, 0, stream>>>(yw, f1s, bias, out);
  } else {
    ks_naive<<<NT, 256, 0, stream>>>(x, f0, f1, bias, out);
  }
}